// Round 3
// baseline (398.281 us; speedup 1.0000x reference)
//
#include <hip/hip_runtime.h>
#include <math.h>

// TreeBackbone fused — round 3.
//  conv: task=(c,py,h), rows via 9x ds_read_b64 (uniform h path), weights 7x b128.
//  pool: [45][14][16] fp32, channel stride 228 (=4 mod 32 -> conflict-free tree b128).
//  tree: thread=(gh,f) loads 32 pool floats once, accumulates all 16 'o' (kills 16x
//        LDS redundancy); tw pre-converted to bf16 padded [gh][f][o][32] in d_ws
//        (halves per-block L2 bytes); LDS partial reduce (stride 17, odd).

#define BLOCK 384
#define NTW2 (21 * 15 * 16 * 32)   // 161280 bf16 elements = 322560 B

__device__ __forceinline__ float sigmoidf_(float v) {
    return 1.0f / (1.0f + __expf(-v));
}

__global__ __launch_bounds__(256) void prep_tw_bf16(
    const float* __restrict__ tw, ushort* __restrict__ tw2)
{
    int i = blockIdx.x * 256 + threadIdx.x;
    if (i >= NTW2) return;
    int col = i & 31, ghfo = i >> 5;
    int o = ghfo & 15, ghf = ghfo >> 4;
    int f = ghf % 15, gh = ghf / 15;
    int g = gh / 7, h = gh % 7;
    int px = col & 15, i2 = col >> 4;
    float v = 0.0f;
    if (px < 14)
        v = tw[o * 8820 + f * 588 + g * 196 + h * 28 + (px >> 1) * 4 + i2 * 2 + (px & 1)];
    unsigned bb = __float_as_uint(v);
    bb += 0x7fffu + ((bb >> 16) & 1u);       // RNE to bf16
    tw2[i] = (ushort)(bb >> 16);
}

template<int USE_BF16>
__global__ __launch_bounds__(BLOCK, 3) void tree_backbone_fused(
    const float* __restrict__ x,    // (B,3,32,32)
    const float* __restrict__ cw,   // (45,25)
    const float* __restrict__ cb,   // (45,)
    const float* __restrict__ tw,   // (16,15,3,7,7,2,2) fp32 (fallback)
    const ushort* __restrict__ tw2, // bf16 [gh][f][o][32] (main)
    const float* __restrict__ tb,   // (336,)
    float* __restrict__ out,        // (B,336)
    int B)
{
    __shared__ float s_pool[45 * 228];   // [c][py][16] + 4-float channel pad
    __shared__ float s_cb[45];
    __shared__ char  s_mix[21420];       // conv: s_x(13824)+s_cw(5040); tree: s_part(315*17*4)
    float* s_x    = (float*)s_mix;               // [3][32 interleaved rows][36]
    float* s_cw   = (float*)(s_mix + 13824);     // [45][28]
    float* s_part = (float*)s_mix;               // [315][17]

    const int b = blockIdx.x;
    if (b >= B) return;
    const int t = threadIdx.x;

    // ---- stage image: interleaved rows p(r)=16(r&1)+(r>>1) ----
    {
        const float4* xs = (const float4*)(x + (size_t)b * 3072);
        #pragma unroll
        for (int jj = 0; jj < 2; ++jj) {
            const int i = t + jj * BLOCK;          // 0..767
            const float4 v = xs[i];
            const int g = i >> 8, rem = i & 255, r = rem >> 3, q = rem & 7;
            const int p = ((r & 1) << 4) + (r >> 1);
            *(float4*)&s_x[(g * 32 + p) * 36 + q * 4] = v;
        }
    }
    for (int i = t; i < 1125; i += BLOCK) s_cw[(i / 25) * 28 + (i % 25)] = cw[i];
    if (t < 45) s_cb[t] = cb[t];
    // zero pool pad cols 14,15 (read by tree b128 path; avoid NaN*0)
    for (int i = t; i < 630; i += BLOCK) {
        int c = i / 14, py = i % 14;
        *(float2*)&s_pool[c * 228 + py * 16 + 14] = make_float2(0.f, 0.f);
    }
    __syncthreads();

    // ---- conv + pool + sigmoid: 1260 tasks = (c, py, h) ----
    for (int task = t; task < 1260; task += BLOCK) {
        const int c = task / 28, r = task % 28, py = r >> 1, h = r & 1;
        const int g = c / 15;
        float w[28];
        #pragma unroll
        for (int k = 0; k < 7; ++k)
            *(float4*)&w[4 * k] = *(const float4*)&s_cw[c * 28 + 4 * k];
        float aA[14], aB[14];
        #pragma unroll
        for (int d = 0; d < 14; ++d) { aA[d] = 0.f; aB[d] = 0.f; }
        #pragma unroll
        for (int dr = 0; dr < 6; ++dr) {
            // logical row 2py+dr -> phys p; read 18 floats from col 14h (8B-aligned)
            const float* rp = &s_x[(g * 32 + ((dr & 1) << 4) + py + (dr >> 1)) * 36 + 14 * h];
            float f[18];
            #pragma unroll
            for (int k = 0; k < 9; ++k)
                *(float2*)&f[2 * k] = *(const float2*)&rp[2 * k];
            if (dr <= 4) {
                #pragma unroll
                for (int kx = 0; kx < 5; ++kx) {
                    const float wv = w[dr * 5 + kx];
                    #pragma unroll
                    for (int d = 0; d < 14; ++d) aA[d] += f[d + kx] * wv;
                }
            }
            if (dr >= 1) {
                #pragma unroll
                for (int kx = 0; kx < 5; ++kx) {
                    const float wv = w[(dr - 1) * 5 + kx];
                    #pragma unroll
                    for (int d = 0; d < 14; ++d) aB[d] += f[d + kx] * wv;
                }
            }
        }
        const float cbias = s_cb[c];
        float* dst = &s_pool[c * 228 + py * 16 + 7 * h];
        #pragma unroll
        for (int p2 = 0; p2 < 7; ++p2) {
            float m = fmaxf(fmaxf(aA[2 * p2], aA[2 * p2 + 1]),
                            fmaxf(aB[2 * p2], aB[2 * p2 + 1]));
            dst[p2] = sigmoidf_(m + cbias);
        }
    }
    __syncthreads();

    // ---- tree partials: thread t<315 = (gh, f); 32 pool floats once, all 16 o ----
    if (t < 315) {
        const int f = t % 15, gh = t / 15, g = gh / 7, h = gh % 7;
        const int c = g * 15 + f;
        float p[32];
        #pragma unroll
        for (int k = 0; k < 8; ++k)
            *(float4*)&p[4 * k] = *(const float4*)&s_pool[c * 228 + 32 * h + 4 * k];
        float acc[16];
        if (USE_BF16) {
            const uint4* wq = (const uint4*)(tw2 + (size_t)t * 16 * 32);
            #pragma unroll
            for (int o = 0; o < 16; ++o) {
                float a = 0.f;
                #pragma unroll
                for (int k = 0; k < 4; ++k) {
                    const uint4 u = wq[o * 4 + k];
                    a += p[8*k+0] * __uint_as_float(u.x << 16) + p[8*k+1] * __uint_as_float(u.x & 0xffff0000u);
                    a += p[8*k+2] * __uint_as_float(u.y << 16) + p[8*k+3] * __uint_as_float(u.y & 0xffff0000u);
                    a += p[8*k+4] * __uint_as_float(u.z << 16) + p[8*k+5] * __uint_as_float(u.z & 0xffff0000u);
                    a += p[8*k+6] * __uint_as_float(u.w << 16) + p[8*k+7] * __uint_as_float(u.w & 0xffff0000u);
                }
                acc[o] = a;
            }
        } else {
            const float* wp = tw + f * 588 + g * 196 + h * 28;
            #pragma unroll
            for (int o = 0; o < 16; ++o) {
                const float4* wf = (const float4*)(wp + o * 8820);
                float a = 0.f;
                #pragma unroll
                for (int w2 = 0; w2 < 7; ++w2) {
                    const float4 q = wf[w2];
                    a += p[2*w2] * q.x + p[2*w2+1] * q.y + p[16+2*w2] * q.z + p[17+2*w2] * q.w;
                }
                acc[o] = a;
            }
        }
        #pragma unroll
        for (int o = 0; o < 16; ++o) s_part[t * 17 + o] = acc[o];
    }
    __syncthreads();

    // ---- final reduce over f + bias + sigmoid ----
    if (t < 336) {
        const int o = t / 21, gh = t % 21;
        float a = 0.f;
        #pragma unroll
        for (int f = 0; f < 15; ++f) a += s_part[(gh * 15 + f) * 17 + o];
        out[(size_t)b * 336 + t] = sigmoidf_(a + tb[t]);
    }
}

extern "C" void kernel_launch(void* const* d_in, const int* in_sizes, int n_in,
                              void* d_out, int out_size, void* d_ws, size_t ws_size,
                              hipStream_t stream) {
    const float* x  = (const float*)d_in[0];
    const float* cw = (const float*)d_in[1];
    const float* cb = (const float*)d_in[2];
    const float* tw = (const float*)d_in[3];
    const float* tb = (const float*)d_in[4];
    float* out = (float*)d_out;

    const int B = in_sizes[0] / 3072;   // 4096
    const bool bf = ws_size >= (size_t)NTW2 * sizeof(ushort);
    if (bf) {
        prep_tw_bf16<<<(NTW2 + 255) / 256, 256, 0, stream>>>(tw, (ushort*)d_ws);
        tree_backbone_fused<1><<<B, BLOCK, 0, stream>>>(
            x, cw, cb, tw, (const ushort*)d_ws, tb, out, B);
    } else {
        tree_backbone_fused<0><<<B, BLOCK, 0, stream>>>(
            x, cw, cb, tw, (const ushort*)d_ws, tb, out, B);
    }
}

// Round 4
// 288.748 us; speedup vs baseline: 1.3793x; 1.3793x over previous
//
#include <hip/hip_runtime.h>
#include <math.h>

// TreeBackbone fused — round 4.
//  conv: round-2 verbatim (template<H>, interleaved s_x rows stride 36 -> conflict-free b128).
//  tree: thread=(gh,f) keeps 28 pool floats + all 16 'o' accs in registers (kills the
//        420x16 scalar-LDS redundancy of round 2). Weights bf16, TRANSPOSED layout
//        chunk[k=0..55][t=0..314] (uint4) so each load instr is 64 consecutive lanes
//        = 1024B contiguous (fixes round 3's 64-line-per-instr scatter).
//  reduce over f via LDS stride-9 (odd, conflict-free), split into two o-halves so
//        s_part overlays dead s_x/s_cw and LDS stays 53.8KB -> 3 blocks/CU.

#define BLOCK 320
#define TREE_T 315
#define NCHUNK 56                                   // uint4 chunks per tree thread
#define TW2_USHORTS (TREE_T * NCHUNK * 8)           // 141120 bf16 = 282240 B

__device__ __forceinline__ float sigmoidf_(float v) {
    return 1.0f / (1.0f + __expf(-v));
}

// tw fp32 (o,f,g,h,w,i,j) -> bf16 chunks [k][t][8], element e=8k+j of thread t's
// 448-long stream; e -> (o = e/28, widx = e%28), widx = i*14 + 2w + j (pool order).
__global__ __launch_bounds__(256) void prep_tw_bf16(
    const float* __restrict__ tw, ushort* __restrict__ tw2)
{
    int i = blockIdx.x * 256 + threadIdx.x;
    if (i >= TW2_USHORTS) return;
    const int j  = i & 7;
    const int t  = (i >> 3) % TREE_T;
    const int k  = (i >> 3) / TREE_T;
    const int e  = k * 8 + j;                       // 0..447
    const int o  = e / 28, widx = e % 28;
    const int i2 = widx / 14, rem = widx % 14, w = rem >> 1, jj = rem & 1;
    const int f  = t % 15, gh = t / 15, g = gh / 7, h = gh % 7;
    const float v = tw[o * 8820 + f * 588 + g * 196 + h * 28 + w * 4 + i2 * 2 + jj];
    unsigned bb = __float_as_uint(v);
    bb += 0x7fffu + ((bb >> 16) & 1u);              // RNE to bf16
    tw2[i] = (ushort)(bb >> 16);
}

template<int H>
__device__ __forceinline__ void conv_half(
    const float* sx,          // s_x + g*1152 : [32 phys rows][36]
    const float* wrow,        // s_cw + c*25
    float cbias, int py,
    float* pooldst)           // s_pool + c*196 + py*14 + 7*H
{
    float aA[14], aB[14];
    #pragma unroll
    for (int d = 0; d < 14; ++d) { aA[d] = 0.f; aB[d] = 0.f; }
    #pragma unroll
    for (int dr = 0; dr < 6; ++dr) {
        const float* rp = sx + (((dr & 1) << 4) + py + (dr >> 1)) * 36 + 12 * H;
        float f[20];
        #pragma unroll
        for (int k = 0; k < 5; ++k)
            *(float4*)&f[4 * k] = *(const float4*)&rp[4 * k];
        if (dr <= 4) {
            #pragma unroll
            for (int kx = 0; kx < 5; ++kx) {
                const float w = wrow[dr * 5 + kx];
                #pragma unroll
                for (int d = 0; d < 14; ++d) aA[d] += f[d + kx + 2 * H] * w;
            }
        }
        if (dr >= 1) {
            #pragma unroll
            for (int kx = 0; kx < 5; ++kx) {
                const float w = wrow[(dr - 1) * 5 + kx];
                #pragma unroll
                for (int d = 0; d < 14; ++d) aB[d] += f[d + kx + 2 * H] * w;
            }
        }
    }
    #pragma unroll
    for (int p = 0; p < 7; ++p) {
        float m = fmaxf(fmaxf(aA[2 * p], aA[2 * p + 1]),
                        fmaxf(aB[2 * p], aB[2 * p + 1]));
        pooldst[p] = sigmoidf_(m + cbias);
    }
}

template<int USE_BF16>
__global__ __launch_bounds__(BLOCK, 4) void tree_backbone_fused(
    const float* __restrict__ x,    // (B,3,32,32)
    const float* __restrict__ cw,   // (45,25)
    const float* __restrict__ cb,   // (45,)
    const float* __restrict__ tw,   // fp32 fallback
    const uint4* __restrict__ tw2,  // bf16 chunks [56][315]
    const float* __restrict__ tb,   // (336,)
    float* __restrict__ out,        // (B,336)
    int B)
{
    __shared__ float s_pool[45 * 196];              // 35280 B, [c][py*14+px]
    __shared__ float s_cb[45];                      // 180 B
    __shared__ __align__(16) char s_mix[18336];     // conv: s_x(13824)+s_cw(4500); tree: s_part(11340)
    float* s_x    = (float*)s_mix;                  // [3][32 interleaved][36]
    float* s_cw   = (float*)(s_mix + 13824);        // [45][25] flat
    float* s_part = (float*)s_mix;                  // [315][9]

    const int b = blockIdx.x;
    if (b >= B) return;
    const int t = threadIdx.x;

    // ---- stage image, interleaved rows p(r)=16(r&1)+(r>>1) ----
    {
        const float4* xs = (const float4*)(x + (size_t)b * 3072);
        for (int i = t; i < 768; i += BLOCK) {
            const float4 v = xs[i];
            const int g = i >> 8, rem = i & 255, r = rem >> 3, q = rem & 7;
            const int p = ((r & 1) << 4) + (r >> 1);
            *(float4*)&s_x[(g * 32 + p) * 36 + q * 4] = v;
        }
    }
    for (int i = t; i < 1125; i += BLOCK) s_cw[i] = cw[i];
    if (t < 45) s_cb[t] = cb[t];
    __syncthreads();

    // ---- conv + pool + sigmoid: 1260 tasks = (h-major, c, py) ----
    for (int task = t; task < 1260; task += BLOCK) {
        const int h  = (task >= 630) ? 1 : 0;
        const int tt = task - 630 * h;
        const int c  = tt / 14;
        const int py = tt - c * 14;
        const int g  = c / 15;
        float* dst = s_pool + c * 196 + py * 14 + 7 * h;
        if (h == 0) conv_half<0>(s_x + g * 1152, s_cw + c * 25, s_cb[c], py, dst);
        else        conv_half<1>(s_x + g * 1152, s_cw + c * 25, s_cb[c], py, dst);
    }
    __syncthreads();

    // ---- tree partials: thread t<315 = (gh,f); 28 pool floats once, all 16 o ----
    float acc[16];
    #pragma unroll
    for (int o = 0; o < 16; ++o) acc[o] = 0.f;
    if (t < TREE_T) {
        const int f = t % 15, gh = t / 15, g = gh / 7, h = gh % 7;
        const int c = g * 15 + f;
        float p[28];
        #pragma unroll
        for (int k = 0; k < 7; ++k)
            *(float4*)&p[4 * k] = *(const float4*)&s_pool[c * 196 + 28 * h + 4 * k];

        if (USE_BF16) {
            #pragma unroll
            for (int k = 0; k < NCHUNK; ++k) {
                const uint4 u = tw2[k * TREE_T + t];       // coalesced across lanes
                const int e0 = k * 8;
                acc[(e0+0)/28] += p[(e0+0)%28] * __uint_as_float(u.x << 16);
                acc[(e0+1)/28] += p[(e0+1)%28] * __uint_as_float(u.x & 0xffff0000u);
                acc[(e0+2)/28] += p[(e0+2)%28] * __uint_as_float(u.y << 16);
                acc[(e0+3)/28] += p[(e0+3)%28] * __uint_as_float(u.y & 0xffff0000u);
                acc[(e0+4)/28] += p[(e0+4)%28] * __uint_as_float(u.z << 16);
                acc[(e0+5)/28] += p[(e0+5)%28] * __uint_as_float(u.z & 0xffff0000u);
                acc[(e0+6)/28] += p[(e0+6)%28] * __uint_as_float(u.w << 16);
                acc[(e0+7)/28] += p[(e0+7)%28] * __uint_as_float(u.w & 0xffff0000u);
            }
        } else {
            const float* wp = tw + f * 588 + g * 196 + h * 28;
            #pragma unroll
            for (int o = 0; o < 16; ++o) {
                const float4* wf = (const float4*)(wp + o * 8820);
                float a = 0.f;
                #pragma unroll
                for (int w2 = 0; w2 < 7; ++w2) {
                    const float4 q = wf[w2];
                    a += p[2*w2]    * q.x + p[2*w2+1]  * q.y
                       + p[14+2*w2]* q.z + p[15+2*w2] * q.w;
                }
                acc[o] = a;
            }
        }
    }

    // ---- reduce over f, two o-halves through s_part[315][9] ----
    if (t < TREE_T) {
        #pragma unroll
        for (int o = 0; o < 8; ++o) s_part[t * 9 + o] = acc[o];
    }
    __syncthreads();
    if (t < 168) {
        const int o = t / 21, gh = t % 21;
        float a = 0.f;
        #pragma unroll
        for (int f = 0; f < 15; ++f) a += s_part[(gh * 15 + f) * 9 + o];
        out[(size_t)b * 336 + t] = sigmoidf_(a + tb[t]);
    }
    __syncthreads();
    if (t < TREE_T) {
        #pragma unroll
        for (int o = 8; o < 16; ++o) s_part[t * 9 + (o - 8)] = acc[o];
    }
    __syncthreads();
    if (t < 168) {
        const int idx = 168 + t;
        const int o = idx / 21, gh = idx % 21;
        float a = 0.f;
        #pragma unroll
        for (int f = 0; f < 15; ++f) a += s_part[(gh * 15 + f) * 9 + (o - 8)];
        out[(size_t)b * 336 + idx] = sigmoidf_(a + tb[idx]);
    }
}

extern "C" void kernel_launch(void* const* d_in, const int* in_sizes, int n_in,
                              void* d_out, int out_size, void* d_ws, size_t ws_size,
                              hipStream_t stream) {
    const float* x  = (const float*)d_in[0];
    const float* cw = (const float*)d_in[1];
    const float* cb = (const float*)d_in[2];
    const float* tw = (const float*)d_in[3];
    const float* tb = (const float*)d_in[4];
    float* out = (float*)d_out;

    const int B = in_sizes[0] / 3072;   // 4096
    const bool bf = ws_size >= (size_t)TW2_USHORTS * sizeof(ushort);
    if (bf) {
        prep_tw_bf16<<<(TW2_USHORTS + 255) / 256, 256, 0, stream>>>(tw, (ushort*)d_ws);
        tree_backbone_fused<1><<<B, BLOCK, 0, stream>>>(
            x, cw, cb, tw, (const uint4*)d_ws, tb, out, B);
    } else {
        tree_backbone_fused<0><<<B, BLOCK, 0, stream>>>(
            x, cw, cb, tw, (const uint4*)d_ws, tb, out, B);
    }
}